// Round 2
// baseline (10395.866 us; speedup 1.0000x reference)
//
#include <hip/hip_runtime.h>
#include <math.h>

// Problem constants
#define N_PTS   30000
#define DIM     64
#define K_C     500
#define K_PAD   576            // 3 * 192 (padded centroids: data 0, csq +INF)
#define N_ITERS 1000

// assign tiling: 192x192 tile, 256 threads as 16x16, each thread 12x12
#define TM 192
#define TN 192
#define NTM 157                // ceil(30000/192)
#define NTN 3                  // 576/192
#define NJOBS (NTM * NTN)      // 471
#define SPAD 196               // LDS row stride (floats): %4==0, 4*SPAD%32!=0 (8-way not 16-way on stage)
#define GRID 256               // 1 block/CU, all resident (2*smem > 160KB forbids pairing)

// accumulation
#define NB2 64
#define FPSCALE 262144.0f      // 2^18 (chunk 469 * 5.5 * 2^18 < 2^31)
#define INV_FPSCALE (1.0 / 262144.0)

#define SMEM_BYTES (2 * DIM * SPAD * 4)   // 100352 B; accum ls (64000 B) overlays it

// Pack (distance, idx): u64 min == (min dist, then min idx). Monotone float map.
__device__ __forceinline__ unsigned long long packDI(float d, int idx) {
  unsigned u = __float_as_uint(d);
  u = (u & 0x80000000u) ? ~u : (u | 0x80000000u);
  return ((unsigned long long)u << 32) | (unsigned)idx;
}

// ---------------------------------------------------------------------------
// Grid-wide barrier: epoch-counting, agent-scope acq/rel (same mechanism as
// cooperative grid.sync). All GRID blocks are resident by LDS-capacity
// construction, so arrival is guaranteed. bar[0]=count, bar[64]=epoch.
__device__ __forceinline__ void gridbar(int* bar) {
  __syncthreads();
  if (threadIdx.x == 0) {
    int* cnt = bar;
    int* ep  = bar + 64;
    int e = __hip_atomic_load(ep, __ATOMIC_RELAXED, __HIP_MEMORY_SCOPE_AGENT);
    int old = __hip_atomic_fetch_add(cnt, 1, __ATOMIC_ACQ_REL, __HIP_MEMORY_SCOPE_AGENT);
    if (old == GRID - 1) {
      __hip_atomic_store(cnt, 0, __ATOMIC_RELAXED, __HIP_MEMORY_SCOPE_AGENT);
      __hip_atomic_fetch_add(ep, 1, __ATOMIC_ACQ_REL, __HIP_MEMORY_SCOPE_AGENT);
    } else {
      while (__hip_atomic_load(ep, __ATOMIC_ACQUIRE, __HIP_MEMORY_SCOPE_AGENT) == e) {
        __builtin_amdgcn_s_sleep(2);
      }
    }
  }
  __syncthreads();
}

// ---------------------------------------------------------------------------
__global__ __launch_bounds__(256, 1)
void k_persist(const float* __restrict__ embeds,
               float* __restrict__ cents,                 // [K_PAD][64], rows>=500 zero
               float* __restrict__ csq,                   // [K_PAD]
               float* __restrict__ esq,                   // [N_PTS]
               int* __restrict__ idx,                     // [N_PTS] init -1
               unsigned long long* __restrict__ cand,     // [N_PTS] init ~0
               int* __restrict__ gcnt,                    // [K_C] init 0
               int* __restrict__ psum,                    // [NB2][K_C][64]
               float* __restrict__ cntf,                  // [K_C]
               int* __restrict__ changed,                 // [N_ITERS] init 0
               int* __restrict__ bar,                     // init 0
               float* __restrict__ out) {
  extern __shared__ __align__(16) char smem[];
  float (*As)[SPAD] = (float (*)[SPAD])smem;
  float (*Bs)[SPAD] = (float (*)[SPAD])(smem + (size_t)DIM * SPAD * 4);
  int* ls = (int*)smem;
  const int tid = threadIdx.x;
  const int bid = blockIdx.x;

  // ---- pre-phase: esq for all points, csq for initial (padded) centroids ----
  {
    const int w = bid * 4 + (tid >> 6);   // global wave id, 0..1023
    const int d = tid & 63;
    for (int p = w; p < N_PTS; p += GRID * 4) {
      float v = embeds[(size_t)p * DIM + d];
      float s = v * v;
      #pragma unroll
      for (int m = 1; m < 64; m <<= 1) s += __shfl_xor(s, m, 64);
      if (d == 0) esq[p] = s;
    }
    if (w < K_PAD) {
      float v = (w < K_C) ? cents[(size_t)w * DIM + d] : 0.f;
      float s = v * v;
      #pragma unroll
      for (int m = 1; m < 64; m <<= 1) s += __shfl_xor(s, m, 64);
      if (d == 0) csq[w] = (w < K_C) ? s : INFINITY;
    }
  }
  gridbar(bar);

  // ---- main loop ----
  for (int it = 0; it < N_ITERS; ++it) {
    // ======== phase 1: assignment (471 jobs of 192 pts x 192 cents) ========
    for (int j = bid; j < NJOBS; j += GRID) {
      const int m0 = (j % NTM) * TM;
      const int n0 = (j / NTM) * TN;
      const int tx = tid & 15, ty = tid >> 4;
      __syncthreads();  // protect smem reuse across jobs/phases

      // stage As (transposed): 192 pts x 64 dims, coalesced float4 along d
      #pragma unroll
      for (int l = 0; l < 12; ++l) {
        int e = tid + l * 256;
        int pl = e >> 4, d4 = e & 15;
        int p = m0 + pl;
        float4 v = make_float4(0.f, 0.f, 0.f, 0.f);
        if (p < N_PTS) v = *reinterpret_cast<const float4*>(embeds + (size_t)p * DIM + d4 * 4);
        As[d4 * 4 + 0][pl] = v.x; As[d4 * 4 + 1][pl] = v.y;
        As[d4 * 4 + 2][pl] = v.z; As[d4 * 4 + 3][pl] = v.w;
      }
      // stage Bs: centroid buffer is padded to K_PAD rows -> no guard
      #pragma unroll
      for (int l = 0; l < 12; ++l) {
        int e2 = tid + l * 256;
        int kl = e2 >> 4, d4 = e2 & 15;
        float4 v = *reinterpret_cast<const float4*>(cents + (size_t)(n0 + kl) * DIM + d4 * 4);
        Bs[d4 * 4 + 0][kl] = v.x; Bs[d4 * 4 + 1][kl] = v.y;
        Bs[d4 * 4 + 2][kl] = v.z; Bs[d4 * 4 + 3][kl] = v.w;
      }

      float esq_r[12];
      #pragma unroll
      for (int i = 0; i < 12; ++i) {
        int p = m0 + ty * 12 + i;
        esq_r[i] = (p < N_PTS) ? esq[p] : 0.f;
      }
      __syncthreads();

      float acc[12][12];
      #pragma unroll
      for (int i = 0; i < 12; ++i)
        #pragma unroll
        for (int j2 = 0; j2 < 12; ++j2) acc[i][j2] = 0.f;

      #pragma unroll 4
      for (int d = 0; d < DIM; ++d) {
        float av[12], bv[12];
        #pragma unroll
        for (int q = 0; q < 3; ++q) {
          float4 a = *reinterpret_cast<const float4*>(&As[d][ty * 12 + q * 4]);
          av[q * 4 + 0] = a.x; av[q * 4 + 1] = a.y; av[q * 4 + 2] = a.z; av[q * 4 + 3] = a.w;
          float4 b = *reinterpret_cast<const float4*>(&Bs[d][tx * 12 + q * 4]);
          bv[q * 4 + 0] = b.x; bv[q * 4 + 1] = b.y; bv[q * 4 + 2] = b.z; bv[q * 4 + 3] = b.w;
        }
        #pragma unroll
        for (int i = 0; i < 12; ++i)
          #pragma unroll
          for (int j2 = 0; j2 < 12; ++j2)
            acc[i][j2] = fmaf(av[i], bv[j2], acc[i][j2]);
      }

      // epilogue: distances + running argmin (ascending n, strict '<' = first min)
      float cv[12];
      #pragma unroll
      for (int q = 0; q < 3; ++q) {
        float4 c = *reinterpret_cast<const float4*>(&csq[n0 + tx * 12 + q * 4]);
        cv[q * 4 + 0] = c.x; cv[q * 4 + 1] = c.y; cv[q * 4 + 2] = c.z; cv[q * 4 + 3] = c.w;
      }
      float best[12]; int bidx[12];
      #pragma unroll
      for (int i = 0; i < 12; ++i) { best[i] = INFINITY; bidx[i] = 0; }
      #pragma unroll
      for (int j2 = 0; j2 < 12; ++j2) {
        int n = n0 + tx * 12 + j2;
        #pragma unroll
        for (int i = 0; i < 12; ++i) {
          float dd = (esq_r[i] - 2.0f * acc[i][j2]) + cv[j2];
          if (dd < best[i]) { best[i] = dd; bidx[i] = n; }
        }
      }
      // cross-lane argmin over 16 tx lanes, then cross-block merge via atomicMin
      #pragma unroll
      for (int i = 0; i < 12; ++i) {
        float v = best[i]; int bi = bidx[i];
        #pragma unroll
        for (int s = 1; s < 16; s <<= 1) {
          float ov = __shfl_xor(v, s, 64);
          int   oi = __shfl_xor(bi, s, 64);
          if (ov < v || (ov == v && oi < bi)) { v = ov; bi = oi; }
        }
        if (tx == 0) {
          int p = m0 + ty * 12 + i;
          if (p < N_PTS) atomicMin(&cand[p], packDI(v, bi));
        }
      }
    }
    gridbar(bar);

    // ======== phase 2: fixed-point partial segment sums (128 blocks) ========
    if (bid < NB2 * 2) {
      const int b = bid & (NB2 - 1), y = bid >> 6;
      for (int i = tid; i < K_C * 32; i += 256) ls[i] = 0;
      __syncthreads();
      const int chunk = (N_PTS + NB2 - 1) / NB2;  // 469
      const int p0 = b * chunk;
      const int p1 = min(p0 + chunk, N_PTS);
      const int d = tid & 31, sub = tid >> 5;
      for (int p = p0 + sub; p < p1; p += 8) {
        int k = (int)(unsigned)(cand[p] & 0xFFFFFFFFull);
        float v = embeds[(size_t)p * DIM + y * 32 + d];
        int iv = __float2int_rn(v * FPSCALE);
        atomicAdd(&ls[k * 32 + d], iv);
        if (y == 0 && d == 0) {
          atomicAdd(&gcnt[k], 1);  // int: deterministic
          int old = idx[p];
          if (old != k) { idx[p] = k; changed[it] = 1; }
        }
      }
      __syncthreads();
      for (int i = tid; i < K_C * 32; i += 256) {
        int k = i >> 5, dd = i & 31;
        psum[(size_t)b * (K_C * DIM) + k * DIM + y * 32 + dd] = ls[i];
      }
    }
    gridbar(bar);

    // exact fixed point: identical assignments => identical int sums =>
    // identical centroids; every remaining iteration is identity. Uniform exit.
    if (__hip_atomic_load(&changed[it], __ATOMIC_RELAXED, __HIP_MEMORY_SCOPE_AGENT) == 0)
      break;

    // ======== phase 3: centroid update (waves: k = bid*4 + wave) ========
    {
      const int k = bid * 4 + (tid >> 6), d = tid & 63;
      if (k < K_C) {
        long long s = 0;
        for (int b = 0; b < NB2; ++b)
          s += (long long)psum[(size_t)b * (K_C * DIM) + k * DIM + d];
        int c = gcnt[k];
        float sum_f = (float)((double)s * INV_FPSCALE);
        float nc = sum_f / ((float)c + 1e-6f);  // matches sums / (counts + EPS)
        cents[k * DIM + d] = nc;
        float sq = nc * nc;
        #pragma unroll
        for (int m = 1; m < 64; m <<= 1) sq += __shfl_xor(sq, m, 64);
        if (d == 0) { csq[k] = sq; cntf[k] = (float)c; gcnt[k] = 0; }
        int g = k * 64 + d;                 // 32000 slots >= N_PTS
        if (g < N_PTS) cand[g] = ~0ull;     // reset candidates for next iter
      }
    }
    gridbar(bar);
  }

  // ---- final output: [cents 32000][idx as f32 30000][counts 500] ----
  const int tot = K_C * DIM + N_PTS + K_C;
  for (int g = bid * 256 + tid; g < tot; g += GRID * 256) {
    float v;
    if (g < K_C * DIM) v = cents[g];
    else if (g < K_C * DIM + N_PTS) v = (float)idx[g - K_C * DIM];
    else v = cntf[g - K_C * DIM - N_PTS];
    out[g] = v;
  }
}

// ---------------------------------------------------------------------------
extern "C" void kernel_launch(void* const* d_in, const int* in_sizes, int n_in,
                              void* d_out, int out_size, void* d_ws, size_t ws_size,
                              hipStream_t stream) {
  const float* embeds = (const float*)d_in[0];
  const float* init_c = (const float*)d_in[1];
  float* out = (float*)d_out;

  char* w = (char*)d_ws;
  size_t off = 0;
  auto alloc = [&](size_t bytes) -> void* {
    void* p = w + off;
    off += (bytes + 255) & ~(size_t)255;
    return p;
  };
  float* cents = (float*)alloc((size_t)K_PAD * DIM * sizeof(float));
  float* csq   = (float*)alloc((size_t)K_PAD * sizeof(float));
  float* esq   = (float*)alloc((size_t)N_PTS * sizeof(float));
  int*   idx   = (int*)  alloc((size_t)N_PTS * sizeof(int));
  float* cntf  = (float*)alloc((size_t)K_C * sizeof(float));
  int*   gcnt  = (int*)  alloc((size_t)K_C * sizeof(int));
  int*   psum  = (int*)  alloc((size_t)NB2 * K_C * DIM * sizeof(int));
  unsigned long long* cand = (unsigned long long*)alloc((size_t)N_PTS * sizeof(unsigned long long));
  int*   chg   = (int*)  alloc((size_t)N_ITERS * sizeof(int));
  int*   bar   = (int*)  alloc(256 * sizeof(int));

  // allow >64KB dynamic LDS (160 KiB/CU on gfx950); harmless if redundant
  (void)hipFuncSetAttribute((const void*)k_persist,
                            hipFuncAttributeMaxDynamicSharedMemorySize, SMEM_BYTES);

  hipMemsetAsync(cents, 0, (size_t)K_PAD * DIM * sizeof(float), stream);
  hipMemcpyAsync(cents, init_c, (size_t)K_C * DIM * sizeof(float),
                 hipMemcpyDeviceToDevice, stream);
  hipMemsetAsync(gcnt, 0, (size_t)K_C * sizeof(int), stream);
  hipMemsetAsync(idx, 0xFF, (size_t)N_PTS * sizeof(int), stream);   // -1: changed@it0
  hipMemsetAsync(cand, 0xFF, (size_t)N_PTS * sizeof(unsigned long long), stream);
  hipMemsetAsync(chg, 0, (size_t)N_ITERS * sizeof(int), stream);
  hipMemsetAsync(bar, 0, 256 * sizeof(int), stream);

  k_persist<<<dim3(GRID), dim3(256), SMEM_BYTES, stream>>>(
      embeds, cents, csq, esq, idx, cand, gcnt, psum, cntf, chg, bar, out);
}

// Round 3
// 7593.419 us; speedup vs baseline: 1.3691x; 1.3691x over previous
//
#include <hip/hip_runtime.h>
#include <math.h>

// Problem constants
#define N_PTS   30000
#define DIM     64
#define K_C     500
#define K_PAD   512            // centroid rows padded (data 0, csq +INF)
#define N_ITERS 1000

#define GRID 256               // == CU count; smem > 80KB forces 1 block/CU -> all resident
#define BLK  512               // 8 waves/CU, 2 waves/SIMD

// assign: each block handles 128 points x ALL 512 centroids (two 256-halves)
#define TM    128
#define NTM   235              // ceil(30000/128)
#define SA    132              // As row stride (floats); 132*4B = 33x16B (rows 16B-aligned)
#define SB    260              // Bs row stride (floats); 260*4B 16B-aligned
#define HALF  256

// accum: 64 point-chunks x 2 dim-halves = 128 active blocks
#define NCH   64
#define CHUNK 469              // ceil(30000/64)
#define FPSCALE 262144.0f      // 2^18 (chunk 469 * 5.5 * 2^18 < 2^31)
#define INV_FPSCALE (1.0 / 262144.0)

#define SMEM_BYTES ((DIM * SA + DIM * SB) * 4)   // 100352 B (>81920 -> 1 block/CU)

// barrier layout: arrive[b] at bar[b*32] (128B apart), release at bar[GRID*32]
#define BAR_STRIDE 32
#define BAR_REL_OFF (GRID * BAR_STRIDE)

// ---------------------------------------------------------------------------
// Grid barrier, flag-tree style: every block release-stores its own slot
// (parallel, distinct cachelines); block 0's threads poll all slots, then one
// release-store to a single word that everyone else acquires. All GRID blocks
// are resident by LDS-capacity construction (validated on HW in round 2).
__device__ __forceinline__ void gridbar(int* bar, int n) {
  __syncthreads();
  if (blockIdx.x == 0) {
    const int t = threadIdx.x;
    if (t >= 1 && t < GRID) {
      while (__hip_atomic_load(&bar[t * BAR_STRIDE], __ATOMIC_ACQUIRE,
                               __HIP_MEMORY_SCOPE_AGENT) < n)
        __builtin_amdgcn_s_sleep(2);
    }
    __syncthreads();
    if (t == 0)
      __hip_atomic_store(&bar[BAR_REL_OFF], n, __ATOMIC_RELEASE,
                         __HIP_MEMORY_SCOPE_AGENT);
  } else {
    if (threadIdx.x == 0) {
      __hip_atomic_store(&bar[blockIdx.x * BAR_STRIDE], n, __ATOMIC_RELEASE,
                         __HIP_MEMORY_SCOPE_AGENT);
      while (__hip_atomic_load(&bar[BAR_REL_OFF], __ATOMIC_ACQUIRE,
                               __HIP_MEMORY_SCOPE_AGENT) < n)
        __builtin_amdgcn_s_sleep(2);
    }
    __syncthreads();
  }
}

// ---------------------------------------------------------------------------
__global__ __launch_bounds__(BLK, 2)
void k_persist(const float* __restrict__ embeds,
               float* __restrict__ cents,      // [K_PAD][64], rows >= 500 zeroed
               float* __restrict__ csq,        // [K_PAD]
               float* __restrict__ esq,        // [N_PTS]
               int* __restrict__ idx,          // [N_PTS] init -1
               int* __restrict__ gcnt,         // [K_C] init 0
               int* __restrict__ psum,         // [NCH][K_C][64]
               float* __restrict__ cntf,       // [K_C]
               int* __restrict__ changed,      // [N_ITERS] init 0
               int* __restrict__ bar,          // init 0
               float* __restrict__ out) {
  extern __shared__ __align__(16) char smem[];
  float (*As)[SA] = (float (*)[SA])smem;                       // 64 x 132 f32
  float (*Bs)[SB] = (float (*)[SB])(smem + DIM * SA * 4);      // 64 x 260 f32
  int* ls = (int*)smem;                                        // accum overlay (64 KB)
  long long* lls = (long long*)smem;                           // update overlay (4 KB)
  const int tid = threadIdx.x;
  const int bid = blockIdx.x;
  int bno = 0;

  // ---- pre-phase: esq for all points, csq for initial (padded) centroids ----
  {
    const int w = bid * 8 + (tid >> 6);   // global wave id, 0..2047
    const int d = tid & 63;
    for (int p = w; p < N_PTS; p += GRID * 8) {
      float v = embeds[(size_t)p * DIM + d];
      float s = v * v;
      #pragma unroll
      for (int m = 1; m < 64; m <<= 1) s += __shfl_xor(s, m, 64);
      if (d == 0) esq[p] = s;
    }
    if (w < K_PAD) {
      float v = (w < K_C) ? cents[(size_t)w * DIM + d] : 0.f;
      float s = v * v;
      #pragma unroll
      for (int m = 1; m < 64; m <<= 1) s += __shfl_xor(s, m, 64);
      if (d == 0) csq[w] = (w < K_C) ? s : INFINITY;
    }
  }
  gridbar(bar, ++bno);

  // ---- main loop ----
  for (int it = 0; it < N_ITERS; ++it) {
    // ======== phase 1: assignment (blocks 0..234, one 128x512 job each) ======
    if (bid < NTM) {
      const int m0 = bid * TM;
      const int tx = tid & 31, ty = tid >> 5;   // 32 x 16 thread grid

      // stage As (transposed): 128 pts x 64 dims, coalesced float4 along d
      #pragma unroll
      for (int l = 0; l < 4; ++l) {
        int e = tid + l * BLK;          // 0..2047
        int pl = e >> 4, d4 = e & 15;
        int p = m0 + pl;
        float4 v = make_float4(0.f, 0.f, 0.f, 0.f);
        if (p < N_PTS) v = *reinterpret_cast<const float4*>(embeds + (size_t)p * DIM + d4 * 4);
        As[d4 * 4 + 0][pl] = v.x; As[d4 * 4 + 1][pl] = v.y;
        As[d4 * 4 + 2][pl] = v.z; As[d4 * 4 + 3][pl] = v.w;
      }
      float esq_r[8];
      #pragma unroll
      for (int i = 0; i < 8; ++i) {
        int p = m0 + ty * 8 + i;
        esq_r[i] = (p < N_PTS) ? esq[p] : 0.f;
      }

      float best[8]; int bidx[8];
      #pragma unroll
      for (int i = 0; i < 8; ++i) { best[i] = INFINITY; bidx[i] = 0; }

      for (int h = 0; h < 2; ++h) {     // two centroid halves, ascending n
        __syncthreads();                // As ready (h=0) / Bs reuse safe (h=1)
        #pragma unroll
        for (int l = 0; l < 8; ++l) {
          int e2 = tid + l * BLK;       // 0..4095
          int kl = e2 >> 4, d4 = e2 & 15;
          float4 v = *reinterpret_cast<const float4*>(
              cents + (size_t)(h * HALF + kl) * DIM + d4 * 4);
          Bs[d4 * 4 + 0][kl] = v.x; Bs[d4 * 4 + 1][kl] = v.y;
          Bs[d4 * 4 + 2][kl] = v.z; Bs[d4 * 4 + 3][kl] = v.w;
        }
        __syncthreads();

        float acc[8][8];
        #pragma unroll
        for (int i = 0; i < 8; ++i)
          #pragma unroll
          for (int j = 0; j < 8; ++j) acc[i][j] = 0.f;

        #pragma unroll 8
        for (int d = 0; d < DIM; ++d) {
          float4 a0 = *reinterpret_cast<const float4*>(&As[d][ty * 8]);
          float4 a1 = *reinterpret_cast<const float4*>(&As[d][ty * 8 + 4]);
          float4 b0 = *reinterpret_cast<const float4*>(&Bs[d][tx * 8]);
          float4 b1 = *reinterpret_cast<const float4*>(&Bs[d][tx * 8 + 4]);
          float av[8] = {a0.x, a0.y, a0.z, a0.w, a1.x, a1.y, a1.z, a1.w};
          float bv[8] = {b0.x, b0.y, b0.z, b0.w, b1.x, b1.y, b1.z, b1.w};
          #pragma unroll
          for (int i = 0; i < 8; ++i)
            #pragma unroll
            for (int j = 0; j < 8; ++j)
              acc[i][j] = fmaf(av[i], bv[j], acc[i][j]);
        }

        // distances + running argmin (ascending n, strict '<' keeps first)
        const int nbase = h * HALF;
        float4 c0 = *reinterpret_cast<const float4*>(&csq[nbase + tx * 8]);
        float4 c1 = *reinterpret_cast<const float4*>(&csq[nbase + tx * 8 + 4]);
        float cv[8] = {c0.x, c0.y, c0.z, c0.w, c1.x, c1.y, c1.z, c1.w};
        #pragma unroll
        for (int j = 0; j < 8; ++j) {
          int n = nbase + tx * 8 + j;
          #pragma unroll
          for (int i = 0; i < 8; ++i) {
            float dd = (esq_r[i] - 2.0f * acc[i][j]) + cv[j];
            if (dd < best[i]) { best[i] = dd; bidx[i] = n; }
          }
        }
      }

      // cross-lane argmin over 32 tx lanes; write idx + change detection
      #pragma unroll
      for (int i = 0; i < 8; ++i) {
        float v = best[i]; int bi = bidx[i];
        #pragma unroll
        for (int s = 1; s < 32; s <<= 1) {
          float ov = __shfl_xor(v, s, 64);
          int   oi = __shfl_xor(bi, s, 64);
          if (ov < v || (ov == v && oi < bi)) { v = ov; bi = oi; }
        }
        if (tx == 0) {
          int p = m0 + ty * 8 + i;
          if (p < N_PTS && idx[p] != bi) {
            idx[p] = bi;
            __hip_atomic_store(&changed[it], 1, __ATOMIC_RELAXED,
                               __HIP_MEMORY_SCOPE_AGENT);
          }
        }
      }
    }
    gridbar(bar, ++bno);

    // ======== phase 2: fixed-point partial segment sums (blocks 0..127) =====
    if (bid < NCH * 2) {
      const int b = bid & (NCH - 1), y = bid >> 6;
      for (int i = tid; i < K_C * 32; i += BLK) ls[i] = 0;
      __syncthreads();
      const int p0 = b * CHUNK;
      const int p1 = min(p0 + CHUNK, N_PTS);
      const int d = tid & 31, sub = tid >> 5;   // 16 points in flight
      for (int p = p0 + sub; p < p1; p += 16) {
        int k = idx[p];
        float v = embeds[(size_t)p * DIM + y * 32 + d];
        int iv = __float2int_rn(v * FPSCALE);
        atomicAdd(&ls[k * 32 + d], iv);
        if (y == 0 && d == 0) atomicAdd(&gcnt[k], 1);  // int: deterministic
      }
      __syncthreads();
      for (int i = tid; i < K_C * 32; i += BLK) {
        int k = i >> 5, dd = i & 31;
        psum[((size_t)b * K_C + k) * DIM + y * 32 + dd] = ls[i];
      }
    }
    gridbar(bar, ++bno);

    // exact fixed point: identical assignments => identical int sums =>
    // identical centroids; all remaining iterations are identity. Uniform exit.
    if (__hip_atomic_load(&changed[it], __ATOMIC_RELAXED,
                          __HIP_MEMORY_SCOPE_AGENT) == 0)
      break;

    // ======== phase 3: centroid update (blocks 0..249, 2 centroids each) ====
    if (bid < (K_C + 1) / 2) {
      const int sel = tid >> 8;            // 0/1: which centroid of this block
      const int k = bid * 2 + sel;
      const int d = tid & 63, bq = (tid >> 6) & 3;
      long long s = 0;
      for (int b2 = bq; b2 < NCH; b2 += 4)   // 16 partials each; int sum: order-free
        s += (long long)psum[((size_t)b2 * K_C + k) * DIM + d];
      lls[(sel * 4 + bq) * 64 + d] = s;
      __syncthreads();
      if (bq == 0) {
        long long tot = lls[(sel * 4 + 0) * 64 + d] + lls[(sel * 4 + 1) * 64 + d]
                      + lls[(sel * 4 + 2) * 64 + d] + lls[(sel * 4 + 3) * 64 + d];
        int c = gcnt[k];
        float sum_f = (float)((double)tot * INV_FPSCALE);
        float nc = sum_f / ((float)c + 1e-6f);   // matches sums / (counts + EPS)
        cents[(size_t)k * DIM + d] = nc;
        float sq = nc * nc;
        #pragma unroll
        for (int m = 1; m < 64; m <<= 1) sq += __shfl_xor(sq, m, 64);
        if (d == 0) { csq[k] = sq; cntf[k] = (float)c; gcnt[k] = 0; }
      }
    }
    gridbar(bar, ++bno);
  }

  // ---- final output: [cents 32000][idx as f32 30000][counts 500] ----
  const int tot = K_C * DIM + N_PTS + K_C;
  for (int g = bid * BLK + tid; g < tot; g += GRID * BLK) {
    float v;
    if (g < K_C * DIM) v = cents[g];
    else if (g < K_C * DIM + N_PTS) v = (float)idx[g - K_C * DIM];
    else v = cntf[g - K_C * DIM - N_PTS];
    out[g] = v;
  }
}

// ---------------------------------------------------------------------------
extern "C" void kernel_launch(void* const* d_in, const int* in_sizes, int n_in,
                              void* d_out, int out_size, void* d_ws, size_t ws_size,
                              hipStream_t stream) {
  const float* embeds = (const float*)d_in[0];
  const float* init_c = (const float*)d_in[1];
  float* out = (float*)d_out;

  char* w = (char*)d_ws;
  size_t off = 0;
  auto alloc = [&](size_t bytes) -> void* {
    void* p = w + off;
    off += (bytes + 255) & ~(size_t)255;
    return p;
  };
  float* cents = (float*)alloc((size_t)K_PAD * DIM * sizeof(float));
  float* csq   = (float*)alloc((size_t)K_PAD * sizeof(float));
  float* esq   = (float*)alloc((size_t)N_PTS * sizeof(float));
  int*   idx   = (int*)  alloc((size_t)N_PTS * sizeof(int));
  float* cntf  = (float*)alloc((size_t)K_C * sizeof(float));
  int*   gcnt  = (int*)  alloc((size_t)K_C * sizeof(int));
  int*   psum  = (int*)  alloc((size_t)NCH * K_C * DIM * sizeof(int));
  int*   chg   = (int*)  alloc((size_t)N_ITERS * sizeof(int));
  int*   bar   = (int*)  alloc((size_t)(BAR_REL_OFF + 64) * sizeof(int));

  // allow >64KB dynamic LDS (160 KiB/CU on gfx950)
  (void)hipFuncSetAttribute((const void*)k_persist,
                            hipFuncAttributeMaxDynamicSharedMemorySize, SMEM_BYTES);

  hipMemsetAsync(cents, 0, (size_t)K_PAD * DIM * sizeof(float), stream);
  hipMemcpyAsync(cents, init_c, (size_t)K_C * DIM * sizeof(float),
                 hipMemcpyDeviceToDevice, stream);
  hipMemsetAsync(gcnt, 0, (size_t)K_C * sizeof(int), stream);
  hipMemsetAsync(idx, 0xFF, (size_t)N_PTS * sizeof(int), stream);  // -1: changed@it0
  hipMemsetAsync(chg, 0, (size_t)N_ITERS * sizeof(int), stream);
  hipMemsetAsync(bar, 0, (size_t)(BAR_REL_OFF + 64) * sizeof(int), stream);

  k_persist<<<dim3(GRID), dim3(BLK), SMEM_BYTES, stream>>>(
      embeds, cents, csq, esq, idx, gcnt, psum, cntf, chg, bar, out);
}

// Round 4
// 4684.660 us; speedup vs baseline: 2.2191x; 1.6209x over previous
//
#include <hip/hip_runtime.h>
#include <math.h>

// Problem constants
#define N_PTS   30000
#define DIM     64
#define K_C     500
#define K_PAD   512            // centroid rows padded (data 0, csq +INF)
#define N_ITERS 1000

#define GRID 256               // == CU count; smem > 80KB forces 1 block/CU -> all resident
#define BLK  512               // 8 waves/CU, 2 waves/SIMD

// assign: each block handles 128 points x ALL 512 centroids (two 256-halves)
#define TM    128
#define NTM   235              // ceil(30000/128)
#define SA    132              // As row stride (floats); rows 16B-aligned
#define SB    260              // Bs row stride (floats); rows 16B-aligned
#define HALF  256

// accum: 64 point-chunks x 4 dim-quarters = 256 active blocks
#define NCH   64
#define CHUNK 469              // ceil(30000/64)
#define FPSCALE 262144.0f      // 2^18 (chunk 469 * 5.5 * 2^18 < 2^31)
#define INV_FPSCALE (1.0 / 262144.0)

#define SMEM_BYTES ((DIM * SA + DIM * SB) * 4)   // 100352 B (>81920 -> 1 block/CU)

// barrier layout: arrive[b] at bar[b*32] (128B apart), release at bar[GRID*32]
#define BAR_STRIDE 32
#define BAR_REL_OFF (GRID * BAR_STRIDE)

// ---------------------------------------------------------------------------
// Grid barrier. Arrival: one release-store per block (parallel, distinct
// cachelines). Block 0 polls all slots with RELAXED scoped loads (reads the
// coherence point WITHOUT per-poll L2 invalidation), then a single acquire
// fence; one release-store releases everyone, who also poll RELAXED + one
// acquire fence. All GRID blocks resident by LDS-capacity construction
// (validated on HW rounds 2-3).
__device__ __forceinline__ void gridbar(int* bar, int n) {
  __syncthreads();
  if (blockIdx.x == 0) {
    const int t = threadIdx.x;
    if (t >= 1 && t < GRID) {
      while (__hip_atomic_load(&bar[t * BAR_STRIDE], __ATOMIC_RELAXED,
                               __HIP_MEMORY_SCOPE_AGENT) < n)
        __builtin_amdgcn_s_sleep(2);
      __builtin_amdgcn_fence(__ATOMIC_ACQUIRE, "agent");  // one inv, not per-poll
    }
    __syncthreads();
    if (t == 0)
      __hip_atomic_store(&bar[BAR_REL_OFF], n, __ATOMIC_RELEASE,
                         __HIP_MEMORY_SCOPE_AGENT);
  } else {
    if (threadIdx.x == 0) {
      __hip_atomic_store(&bar[blockIdx.x * BAR_STRIDE], n, __ATOMIC_RELEASE,
                         __HIP_MEMORY_SCOPE_AGENT);
      while (__hip_atomic_load(&bar[BAR_REL_OFF], __ATOMIC_RELAXED,
                               __HIP_MEMORY_SCOPE_AGENT) < n)
        __builtin_amdgcn_s_sleep(2);
      __builtin_amdgcn_fence(__ATOMIC_ACQUIRE, "agent");
    }
    __syncthreads();
  }
}

// ---------------------------------------------------------------------------
__global__ __launch_bounds__(BLK, 2)
void k_persist(const float* __restrict__ embeds,
               float* __restrict__ cents,      // [K_PAD][64], rows >= 500 zeroed
               float* __restrict__ csq,        // [K_PAD]
               float* __restrict__ esq,        // [N_PTS]
               int* __restrict__ idx,          // [N_PTS] init -1
               int* __restrict__ gcnt,         // [K_C] init 0
               int* __restrict__ psum,         // [NCH][K_C][64]
               float* __restrict__ cntf,       // [K_C]
               int* __restrict__ changed,      // [N_ITERS] init 0
               int* __restrict__ bar,          // init 0
               float* __restrict__ out) {
  extern __shared__ __align__(16) char smem[];
  float (*As)[SA] = (float (*)[SA])smem;                       // 64 x 132 f32
  float (*Bs)[SB] = (float (*)[SB])(smem + DIM * SA * 4);      // 64 x 260 f32
  int* ls = (int*)smem;                                        // accum overlay (32 KB)
  long long* lls = (long long*)smem;                           // update overlay (4 KB)
  const int tid = threadIdx.x;
  const int bid = blockIdx.x;
  int bno = 0;

  // ---- pre-phase: esq for all points, csq for initial (padded) centroids ----
  {
    const int w = bid * 8 + (tid >> 6);   // global wave id, 0..2047
    const int d = tid & 63;
    for (int p = w; p < N_PTS; p += GRID * 8) {
      float v = embeds[(size_t)p * DIM + d];
      float s = v * v;
      #pragma unroll
      for (int m = 1; m < 64; m <<= 1) s += __shfl_xor(s, m, 64);
      if (d == 0) esq[p] = s;
    }
    if (w < K_PAD) {
      float v = (w < K_C) ? cents[(size_t)w * DIM + d] : 0.f;
      float s = v * v;
      #pragma unroll
      for (int m = 1; m < 64; m <<= 1) s += __shfl_xor(s, m, 64);
      if (d == 0) csq[w] = (w < K_C) ? s : INFINITY;
    }
  }
  gridbar(bar, ++bno);

  // ---- main loop ----
  for (int it = 0; it < N_ITERS; ++it) {
    // ======== phase 1: assignment (blocks 0..234, one 128x512 job each) ======
    if (bid < NTM) {
      const int m0 = bid * TM;
      const int tx = tid & 31, ty = tid >> 5;   // 32 x 16 thread grid

      // stage As (transposed): 128 pts x 64 dims, coalesced float4 along d
      #pragma unroll
      for (int l = 0; l < 4; ++l) {
        int e = tid + l * BLK;          // 0..2047
        int pl = e >> 4, d4 = e & 15;
        int p = m0 + pl;
        float4 v = make_float4(0.f, 0.f, 0.f, 0.f);
        if (p < N_PTS) v = *reinterpret_cast<const float4*>(embeds + (size_t)p * DIM + d4 * 4);
        As[d4 * 4 + 0][pl] = v.x; As[d4 * 4 + 1][pl] = v.y;
        As[d4 * 4 + 2][pl] = v.z; As[d4 * 4 + 3][pl] = v.w;
      }
      float esq_r[8];
      #pragma unroll
      for (int i = 0; i < 8; ++i) {
        int p = m0 + ty * 8 + i;
        esq_r[i] = (p < N_PTS) ? esq[p] : 0.f;
      }

      float best[8]; int bidx[8];
      #pragma unroll
      for (int i = 0; i < 8; ++i) { best[i] = INFINITY; bidx[i] = 0; }

      for (int h = 0; h < 2; ++h) {     // two centroid halves, ascending n
        __syncthreads();                // As ready (h=0) / Bs reuse safe (h=1)
        #pragma unroll
        for (int l = 0; l < 8; ++l) {
          int e2 = tid + l * BLK;       // 0..4095
          int kl = e2 >> 4, d4 = e2 & 15;
          float4 v = *reinterpret_cast<const float4*>(
              cents + (size_t)(h * HALF + kl) * DIM + d4 * 4);
          Bs[d4 * 4 + 0][kl] = v.x; Bs[d4 * 4 + 1][kl] = v.y;
          Bs[d4 * 4 + 2][kl] = v.z; Bs[d4 * 4 + 3][kl] = v.w;
        }
        __syncthreads();

        float acc[8][8];
        #pragma unroll
        for (int i = 0; i < 8; ++i)
          #pragma unroll
          for (int j = 0; j < 8; ++j) acc[i][j] = 0.f;

        // per-thread columns: 4 at tx*4, 4 at 128+tx*4 -> lanes read
        // CONSECUTIVE 16B units (conflict-free), unlike the old 32B stride
        #pragma unroll 8
        for (int d = 0; d < DIM; ++d) {
          float4 a0 = *reinterpret_cast<const float4*>(&As[d][ty * 8]);
          float4 a1 = *reinterpret_cast<const float4*>(&As[d][ty * 8 + 4]);
          float4 b0 = *reinterpret_cast<const float4*>(&Bs[d][tx * 4]);
          float4 b1 = *reinterpret_cast<const float4*>(&Bs[d][128 + tx * 4]);
          float av[8] = {a0.x, a0.y, a0.z, a0.w, a1.x, a1.y, a1.z, a1.w};
          float bv[8] = {b0.x, b0.y, b0.z, b0.w, b1.x, b1.y, b1.z, b1.w};
          #pragma unroll
          for (int i = 0; i < 8; ++i)
            #pragma unroll
            for (int j = 0; j < 8; ++j)
              acc[i][j] = fmaf(av[i], bv[j], acc[i][j]);
        }

        // distances + running argmin (n ascending within thread, strict '<')
        const int nbase = h * HALF;
        float4 c0 = *reinterpret_cast<const float4*>(&csq[nbase + tx * 4]);
        float4 c1 = *reinterpret_cast<const float4*>(&csq[nbase + 128 + tx * 4]);
        float cv[8] = {c0.x, c0.y, c0.z, c0.w, c1.x, c1.y, c1.z, c1.w};
        #pragma unroll
        for (int g = 0; g < 2; ++g) {
          #pragma unroll
          for (int j = 0; j < 4; ++j) {
            int c = g * 4 + j;
            int n = nbase + g * 128 + tx * 4 + j;
            #pragma unroll
            for (int i = 0; i < 8; ++i) {
              float dd = (esq_r[i] - 2.0f * acc[i][c]) + cv[c];
              if (dd < best[i]) { best[i] = dd; bidx[i] = n; }
            }
          }
        }
      }

      // cross-lane argmin over 32 tx lanes; write idx + change detection
      #pragma unroll
      for (int i = 0; i < 8; ++i) {
        float v = best[i]; int bi = bidx[i];
        #pragma unroll
        for (int s = 1; s < 32; s <<= 1) {
          float ov = __shfl_xor(v, s, 64);
          int   oi = __shfl_xor(bi, s, 64);
          if (ov < v || (ov == v && oi < bi)) { v = ov; bi = oi; }
        }
        if (tx == 0) {
          int p = m0 + ty * 8 + i;
          if (p < N_PTS && idx[p] != bi) {
            idx[p] = bi;
            __hip_atomic_store(&changed[it], 1, __ATOMIC_RELAXED,
                               __HIP_MEMORY_SCOPE_AGENT);
          }
        }
      }
    }
    gridbar(bar, ++bno);

    // ======== phase 2: fixed-point partial sums (all 256 blocks) ============
    {
      const int b = bid & (NCH - 1), y = bid >> 6;   // y: dim quarter 0..3
      for (int i = tid; i < K_C * 16; i += BLK) ls[i] = 0;
      __syncthreads();
      const int p0 = b * CHUNK;
      const int p1 = min(p0 + CHUNK, N_PTS);
      const int d = tid & 15, sub = tid >> 4;   // 32 points in flight
      for (int p = p0 + sub; p < p1; p += 32) {
        int k = idx[p];
        float v = embeds[(size_t)p * DIM + y * 16 + d];
        int iv = __float2int_rn(v * FPSCALE);
        atomicAdd(&ls[k * 16 + d], iv);
        if (y == 0 && d == 0) atomicAdd(&gcnt[k], 1);  // int: deterministic
      }
      __syncthreads();
      for (int i = tid; i < K_C * 16; i += BLK) {
        int k = i >> 4, dd = i & 15;
        psum[((size_t)b * K_C + k) * DIM + y * 16 + dd] = ls[i];
      }
    }
    gridbar(bar, ++bno);

    // exact fixed point: identical assignments => identical int sums =>
    // identical centroids; all remaining iterations are identity. Uniform exit.
    if (__hip_atomic_load(&changed[it], __ATOMIC_RELAXED,
                          __HIP_MEMORY_SCOPE_AGENT) == 0)
      break;

    // ======== phase 3: centroid update (blocks 0..249, 2 centroids each) ====
    if (bid < (K_C + 1) / 2) {
      const int sel = tid >> 8;            // 0/1: which centroid of this block
      const int k = bid * 2 + sel;
      const int d = tid & 63, bq = (tid >> 6) & 3;
      long long s = 0;
      for (int b2 = bq; b2 < NCH; b2 += 4)   // 16 partials each; int sum: order-free
        s += (long long)psum[((size_t)b2 * K_C + k) * DIM + d];
      lls[(sel * 4 + bq) * 64 + d] = s;
      __syncthreads();
      if (bq == 0) {
        long long tot = lls[(sel * 4 + 0) * 64 + d] + lls[(sel * 4 + 1) * 64 + d]
                      + lls[(sel * 4 + 2) * 64 + d] + lls[(sel * 4 + 3) * 64 + d];
        int c = gcnt[k];
        float sum_f = (float)((double)tot * INV_FPSCALE);
        float nc = sum_f / ((float)c + 1e-6f);   // matches sums / (counts + EPS)
        cents[(size_t)k * DIM + d] = nc;
        float sq = nc * nc;
        #pragma unroll
        for (int m = 1; m < 64; m <<= 1) sq += __shfl_xor(sq, m, 64);
        if (d == 0) { csq[k] = sq; cntf[k] = (float)c; gcnt[k] = 0; }
      }
    }
    gridbar(bar, ++bno);
  }

  // ---- final output: [cents 32000][idx as f32 30000][counts 500] ----
  const int tot = K_C * DIM + N_PTS + K_C;
  for (int g = bid * BLK + tid; g < tot; g += GRID * BLK) {
    float v;
    if (g < K_C * DIM) v = cents[g];
    else if (g < K_C * DIM + N_PTS) v = (float)idx[g - K_C * DIM];
    else v = cntf[g - K_C * DIM - N_PTS];
    out[g] = v;
  }
}

// ---------------------------------------------------------------------------
extern "C" void kernel_launch(void* const* d_in, const int* in_sizes, int n_in,
                              void* d_out, int out_size, void* d_ws, size_t ws_size,
                              hipStream_t stream) {
  const float* embeds = (const float*)d_in[0];
  const float* init_c = (const float*)d_in[1];
  float* out = (float*)d_out;

  char* w = (char*)d_ws;
  size_t off = 0;
  auto alloc = [&](size_t bytes) -> void* {
    void* p = w + off;
    off += (bytes + 255) & ~(size_t)255;
    return p;
  };
  float* cents = (float*)alloc((size_t)K_PAD * DIM * sizeof(float));
  float* csq   = (float*)alloc((size_t)K_PAD * sizeof(float));
  float* esq   = (float*)alloc((size_t)N_PTS * sizeof(float));
  int*   idx   = (int*)  alloc((size_t)N_PTS * sizeof(int));
  float* cntf  = (float*)alloc((size_t)K_C * sizeof(float));
  int*   gcnt  = (int*)  alloc((size_t)K_C * sizeof(int));
  int*   psum  = (int*)  alloc((size_t)NCH * K_C * DIM * sizeof(int));
  int*   chg   = (int*)  alloc((size_t)N_ITERS * sizeof(int));
  int*   bar   = (int*)  alloc((size_t)(BAR_REL_OFF + 64) * sizeof(int));

  // allow >64KB dynamic LDS (160 KiB/CU on gfx950)
  (void)hipFuncSetAttribute((const void*)k_persist,
                            hipFuncAttributeMaxDynamicSharedMemorySize, SMEM_BYTES);

  hipMemsetAsync(cents, 0, (size_t)K_PAD * DIM * sizeof(float), stream);
  hipMemcpyAsync(cents, init_c, (size_t)K_C * DIM * sizeof(float),
                 hipMemcpyDeviceToDevice, stream);
  hipMemsetAsync(gcnt, 0, (size_t)K_C * sizeof(int), stream);
  hipMemsetAsync(idx, 0xFF, (size_t)N_PTS * sizeof(int), stream);  // -1: changed@it0
  hipMemsetAsync(chg, 0, (size_t)N_ITERS * sizeof(int), stream);
  hipMemsetAsync(bar, 0, (size_t)(BAR_REL_OFF + 64) * sizeof(int), stream);

  k_persist<<<dim3(GRID), dim3(BLK), SMEM_BYTES, stream>>>(
      embeds, cents, csq, esq, idx, gcnt, psum, cntf, chg, bar, out);
}

// Round 5
// 4274.263 us; speedup vs baseline: 2.4322x; 1.0960x over previous
//
#include <hip/hip_runtime.h>
#include <math.h>

// Problem constants
#define N_PTS   30000
#define DIM     64
#define K_C     500
#define K_PAD   512            // centroid rows padded (data 0, csq +INF)
#define N_ITERS 1000

#define GRID 256               // == CU count; smem > 80KB forces 1 block/CU -> all resident
#define BLK  512               // 8 waves/CU, 2 waves/SIMD

// assign: each block handles 128 points x ALL 512 centroids (two 256-halves)
#define TM    128
#define NTM   235              // ceil(30000/128)
#define SA    132              // As row stride (floats); rows 16B-aligned
#define SB    260              // Bs row stride (floats); rows 16B-aligned
#define HALF  256

#define FPSCALE 262144.0f      // 2^18; int64 accumulate: 3e4*5.5*2^18 ~ 4e10 << 2^63
#define INV_FPSCALE (1.0 / 262144.0)

#define SMEM_BYTES ((DIM * SA + DIM * SB) * 4)   // 100352 B (>81920 -> 1 block/CU)

// barrier layout: arrive[b] at bar[b*32] (128B apart), release at bar[GRID*32]
#define BAR_STRIDE 32
#define BAR_REL_OFF (GRID * BAR_STRIDE)

// ---------------------------------------------------------------------------
// Grid barrier (HW-validated rounds 2-4). Arrival: one release-store per block
// (parallel, distinct cachelines). Block 0 polls RELAXED (no per-poll L2
// invalidate), one acquire fence after success, one release-store to the
// release word; spinners poll RELAXED + one acquire fence.
__device__ __forceinline__ void gridbar(int* bar, int n) {
  __syncthreads();
  if (blockIdx.x == 0) {
    const int t = threadIdx.x;
    if (t >= 1 && t < GRID) {
      while (__hip_atomic_load(&bar[t * BAR_STRIDE], __ATOMIC_RELAXED,
                               __HIP_MEMORY_SCOPE_AGENT) < n)
        __builtin_amdgcn_s_sleep(2);
      __builtin_amdgcn_fence(__ATOMIC_ACQUIRE, "agent");
    }
    __syncthreads();
    if (t == 0)
      __hip_atomic_store(&bar[BAR_REL_OFF], n, __ATOMIC_RELEASE,
                         __HIP_MEMORY_SCOPE_AGENT);
  } else {
    if (threadIdx.x == 0) {
      __hip_atomic_store(&bar[blockIdx.x * BAR_STRIDE], n, __ATOMIC_RELEASE,
                         __HIP_MEMORY_SCOPE_AGENT);
      while (__hip_atomic_load(&bar[BAR_REL_OFF], __ATOMIC_RELAXED,
                               __HIP_MEMORY_SCOPE_AGENT) < n)
        __builtin_amdgcn_s_sleep(2);
      __builtin_amdgcn_fence(__ATOMIC_ACQUIRE, "agent");
    }
    __syncthreads();
  }
}

// ---------------------------------------------------------------------------
__global__ __launch_bounds__(BLK, 2)
void k_persist(const float* __restrict__ embeds,
               float* __restrict__ cents,      // [K_PAD][64], rows >= 500 zeroed
               float* __restrict__ csq,        // [K_PAD]
               float* __restrict__ esq,        // [N_PTS]
               int* __restrict__ idx,          // [N_PTS] init -1
               int* __restrict__ gcnt,         // [K_C] init 0
               unsigned long long* __restrict__ acc,  // [K_C][64] int64, init 0
               float* __restrict__ cntf,       // [K_C]
               int* __restrict__ changed,      // [N_ITERS] init 0
               int* __restrict__ bar,          // init 0
               float* __restrict__ out) {
  extern __shared__ __align__(16) char smem[];
  float (*As)[SA] = (float (*)[SA])smem;                       // 64 x 132 f32
  float (*Bs)[SB] = (float (*)[SB])(smem + DIM * SA * 4);      // 64 x 260 f32
  int* bidxs = (int*)(smem + DIM * SA * 4);                    // overlay on Bs (512B)
  const int tid = threadIdx.x;
  const int bid = blockIdx.x;
  int bno = 0;

  // ---- pre-phase: esq for all points, csq for initial (padded) centroids ----
  {
    const int w = bid * 8 + (tid >> 6);   // global wave id, 0..2047
    const int d = tid & 63;
    for (int p = w; p < N_PTS; p += GRID * 8) {
      float v = embeds[(size_t)p * DIM + d];
      float s = v * v;
      #pragma unroll
      for (int m = 1; m < 64; m <<= 1) s += __shfl_xor(s, m, 64);
      if (d == 0) esq[p] = s;
    }
    if (w < K_PAD) {
      float v = (w < K_C) ? cents[(size_t)w * DIM + d] : 0.f;
      float s = v * v;
      #pragma unroll
      for (int m = 1; m < 64; m <<= 1) s += __shfl_xor(s, m, 64);
      if (d == 0) csq[w] = (w < K_C) ? s : INFINITY;
    }
  }
  gridbar(bar, ++bno);

  // ---- main loop ----
  for (int it = 0; it < N_ITERS; ++it) {
    // ===== phase A: assignment + fused accumulation (blocks 0..234) =========
    if (bid < NTM) {
      const int m0 = bid * TM;
      const int tx = tid & 31, ty = tid >> 5;   // 32 x 16 thread grid

      // stage As (transposed). Lane->column mapping: within a wave pl is
      // consecutive -> LDS banks 2-way (free). Global strided 16B reads are
      // L2-hot (32KB/block, persistent block on same XCD).
      #pragma unroll
      for (int l = 0; l < 4; ++l) {
        int e = tid + l * BLK;          // 0..2047
        int pl = e & 127, d4 = e >> 7;
        int p = m0 + pl;
        float4 v = make_float4(0.f, 0.f, 0.f, 0.f);
        if (p < N_PTS) v = *reinterpret_cast<const float4*>(embeds + (size_t)p * DIM + d4 * 4);
        As[d4 * 4 + 0][pl] = v.x; As[d4 * 4 + 1][pl] = v.y;
        As[d4 * 4 + 2][pl] = v.z; As[d4 * 4 + 3][pl] = v.w;
      }
      float esq_r[8];
      #pragma unroll
      for (int i = 0; i < 8; ++i) {
        int p = m0 + ty * 8 + i;
        esq_r[i] = (p < N_PTS) ? esq[p] : 0.f;
      }

      float best[8]; int bidx[8];
      #pragma unroll
      for (int i = 0; i < 8; ++i) { best[i] = INFINITY; bidx[i] = 0; }

      for (int h = 0; h < 2; ++h) {     // two centroid halves, ascending n
        __syncthreads();                // As ready (h=0) / Bs reuse safe (h=1)
        #pragma unroll
        for (int l = 0; l < 8; ++l) {
          int e2 = tid + l * BLK;       // 0..4095
          int kl = e2 & 255, d4 = e2 >> 8;
          float4 v = *reinterpret_cast<const float4*>(
              cents + (size_t)(h * HALF + kl) * DIM + d4 * 4);
          Bs[d4 * 4 + 0][kl] = v.x; Bs[d4 * 4 + 1][kl] = v.y;
          Bs[d4 * 4 + 2][kl] = v.z; Bs[d4 * 4 + 3][kl] = v.w;
        }
        __syncthreads();

        float acc_r[8][8];
        #pragma unroll
        for (int i = 0; i < 8; ++i)
          #pragma unroll
          for (int j = 0; j < 8; ++j) acc_r[i][j] = 0.f;

        #pragma unroll 8
        for (int d = 0; d < DIM; ++d) {
          float4 a0 = *reinterpret_cast<const float4*>(&As[d][ty * 8]);
          float4 a1 = *reinterpret_cast<const float4*>(&As[d][ty * 8 + 4]);
          float4 b0 = *reinterpret_cast<const float4*>(&Bs[d][tx * 4]);
          float4 b1 = *reinterpret_cast<const float4*>(&Bs[d][128 + tx * 4]);
          float av[8] = {a0.x, a0.y, a0.z, a0.w, a1.x, a1.y, a1.z, a1.w};
          float bv[8] = {b0.x, b0.y, b0.z, b0.w, b1.x, b1.y, b1.z, b1.w};
          #pragma unroll
          for (int i = 0; i < 8; ++i)
            #pragma unroll
            for (int j = 0; j < 8; ++j)
              acc_r[i][j] = fmaf(av[i], bv[j], acc_r[i][j]);
        }

        // distances + running argmin (n ascending within thread, strict '<')
        const int nbase = h * HALF;
        float4 c0 = *reinterpret_cast<const float4*>(&csq[nbase + tx * 4]);
        float4 c1 = *reinterpret_cast<const float4*>(&csq[nbase + 128 + tx * 4]);
        float cv[8] = {c0.x, c0.y, c0.z, c0.w, c1.x, c1.y, c1.z, c1.w};
        #pragma unroll
        for (int g = 0; g < 2; ++g) {
          #pragma unroll
          for (int j = 0; j < 4; ++j) {
            int c = g * 4 + j;
            int n = nbase + g * 128 + tx * 4 + j;
            #pragma unroll
            for (int i = 0; i < 8; ++i) {
              float dd = (esq_r[i] - 2.0f * acc_r[i][c]) + cv[c];
              if (dd < best[i]) { best[i] = dd; bidx[i] = n; }
            }
          }
        }
      }

      __syncthreads();   // all Bs reads done before overlaying bidxs on it

      // cross-lane argmin over 32 tx lanes; publish idx + change detection
      #pragma unroll
      for (int i = 0; i < 8; ++i) {
        float v = best[i]; int bi = bidx[i];
        #pragma unroll
        for (int s = 1; s < 32; s <<= 1) {
          float ov = __shfl_xor(v, s, 64);
          int   oi = __shfl_xor(bi, s, 64);
          if (ov < v || (ov == v && oi < bi)) { v = ov; bi = oi; }
        }
        if (tx == 0) {
          int pl = ty * 8 + i, p = m0 + pl;
          bidxs[pl] = bi;
          if (p < N_PTS && idx[p] != bi) {
            idx[p] = bi;
            __hip_atomic_store(&changed[it], 1, __ATOMIC_RELAXED,
                               __HIP_MEMORY_SCOPE_AGENT);
          }
        }
      }
      __syncthreads();   // bidxs visible

      // fused fixed-point accumulation: int64 atomics, order-free exact.
      // wave w handles points w*16..w*16+15; lane = dim.
      {
        const int w = tid >> 6, lane = tid & 63;
        #pragma unroll 4
        for (int i = 0; i < 16; ++i) {
          int pl = w * 16 + i, p = m0 + pl;
          if (p < N_PTS) {
            int k = bidxs[pl];   // LDS broadcast
            float v = embeds[(size_t)p * DIM + lane];
            int iv = __float2int_rn(v * FPSCALE);
            atomicAdd(&acc[(size_t)k * DIM + lane],
                      (unsigned long long)(long long)iv);
            if (lane == 0) atomicAdd(&gcnt[k], 1);
          }
        }
      }
    }
    gridbar(bar, ++bno);

    // exact fixed point: identical assignments => identical int64 sums =>
    // identical centroids; remaining iterations are identity. Uniform exit.
    if (__hip_atomic_load(&changed[it], __ATOMIC_RELAXED,
                          __HIP_MEMORY_SCOPE_AGENT) == 0)
      break;

    // ===== phase B: centroid update (blocks 0..62, 8 centroids each) ========
    if (bid < (K_C + 7) / 8) {
      const int k = bid * 8 + (tid >> 6), d = tid & 63;
      if (k < K_C) {
        long long tot = (long long)acc[(size_t)k * DIM + d];
        int c = gcnt[k];
        float sum_f = (float)((double)tot * INV_FPSCALE);
        float nc = sum_f / ((float)c + 1e-6f);   // matches sums / (counts + EPS)
        cents[(size_t)k * DIM + d] = nc;
        acc[(size_t)k * DIM + d] = 0ull;         // re-arm for next iteration
        float sq = nc * nc;
        #pragma unroll
        for (int m = 1; m < 64; m <<= 1) sq += __shfl_xor(sq, m, 64);
        if (d == 0) { csq[k] = sq; cntf[k] = (float)c; gcnt[k] = 0; }
      }
    }
    gridbar(bar, ++bno);
  }

  // ---- final output: [cents 32000][idx as f32 30000][counts 500] ----
  const int tot = K_C * DIM + N_PTS + K_C;
  for (int g = bid * BLK + tid; g < tot; g += GRID * BLK) {
    float v;
    if (g < K_C * DIM) v = cents[g];
    else if (g < K_C * DIM + N_PTS) v = (float)idx[g - K_C * DIM];
    else v = cntf[g - K_C * DIM - N_PTS];
    out[g] = v;
  }
}

// ---------------------------------------------------------------------------
extern "C" void kernel_launch(void* const* d_in, const int* in_sizes, int n_in,
                              void* d_out, int out_size, void* d_ws, size_t ws_size,
                              hipStream_t stream) {
  const float* embeds = (const float*)d_in[0];
  const float* init_c = (const float*)d_in[1];
  float* out = (float*)d_out;

  char* w = (char*)d_ws;
  size_t off = 0;
  auto alloc = [&](size_t bytes) -> void* {
    void* p = w + off;
    off += (bytes + 255) & ~(size_t)255;
    return p;
  };
  float* cents = (float*)alloc((size_t)K_PAD * DIM * sizeof(float));
  float* csq   = (float*)alloc((size_t)K_PAD * sizeof(float));
  float* esq   = (float*)alloc((size_t)N_PTS * sizeof(float));
  int*   idx   = (int*)  alloc((size_t)N_PTS * sizeof(int));
  float* cntf  = (float*)alloc((size_t)K_C * sizeof(float));
  int*   gcnt  = (int*)  alloc((size_t)K_C * sizeof(int));
  unsigned long long* acc =
      (unsigned long long*)alloc((size_t)K_C * DIM * sizeof(unsigned long long));
  int*   chg   = (int*)  alloc((size_t)N_ITERS * sizeof(int));
  int*   bar   = (int*)  alloc((size_t)(BAR_REL_OFF + 64) * sizeof(int));

  // allow >64KB dynamic LDS (160 KiB/CU on gfx950)
  (void)hipFuncSetAttribute((const void*)k_persist,
                            hipFuncAttributeMaxDynamicSharedMemorySize, SMEM_BYTES);

  hipMemsetAsync(cents, 0, (size_t)K_PAD * DIM * sizeof(float), stream);
  hipMemcpyAsync(cents, init_c, (size_t)K_C * DIM * sizeof(float),
                 hipMemcpyDeviceToDevice, stream);
  hipMemsetAsync(gcnt, 0, (size_t)K_C * sizeof(int), stream);
  hipMemsetAsync(acc, 0, (size_t)K_C * DIM * sizeof(unsigned long long), stream);
  hipMemsetAsync(idx, 0xFF, (size_t)N_PTS * sizeof(int), stream);  // -1: changed@it0
  hipMemsetAsync(chg, 0, (size_t)N_ITERS * sizeof(int), stream);
  hipMemsetAsync(bar, 0, (size_t)(BAR_REL_OFF + 64) * sizeof(int), stream);

  k_persist<<<dim3(GRID), dim3(BLK), SMEM_BYTES, stream>>>(
      embeds, cents, csq, esq, idx, gcnt, acc, cntf, chg, bar, out);
}

// Round 6
// 2091.423 us; speedup vs baseline: 4.9707x; 2.0437x over previous
//
#include <hip/hip_runtime.h>
#include <math.h>

// Problem constants
#define N_PTS   30000
#define DIM     64
#define K_C     500
#define K_PAD   512            // centroid rows padded (data 0, csq +INF)
#define N_ITERS 1000

#define GRID 256               // == CU count; smem > 80KB forces 1 block/CU -> all resident
#define BLK  512               // 8 waves/CU, 2 waves/SIMD

// assign: each block handles 128 points x ALL 512 centroids (two 256-halves)
#define TM    128
#define NTM   235              // ceil(30000/128)
#define SA    132              // As row stride (floats); rows 16B-aligned
#define SB    260              // Bs row stride (floats); rows 16B-aligned
#define HALF  256

#define FPSCALE 262144.0f      // 2^18; int64 accumulate: 3e4*5.5*2^18 ~ 4e10 << 2^63
#define INV_FPSCALE (1.0 / 262144.0)

// LDS: As + Bs + {bidxs[128], chg_pl[128], chg_old[128], chg_cnt[4]}
#define SMEM_BYTES ((DIM * SA + DIM * SB) * 4 + (128 * 3 + 4) * 4)  // 101904 B -> 1 block/CU

// barrier layout: arrive[b] at bar[b*32] (128B apart), release at bar[GRID*32]
#define BAR_STRIDE 32
#define BAR_REL_OFF (GRID * BAR_STRIDE)

// ---------------------------------------------------------------------------
// Grid barrier (HW-validated rounds 2-5). Arrival: one release-store per block
// (parallel, distinct cachelines). Block 0 polls RELAXED (no per-poll L2
// invalidate), one acquire fence after success, one release-store to the
// release word; spinners poll RELAXED + one acquire fence.
__device__ __forceinline__ void gridbar(int* bar, int n) {
  __syncthreads();
  if (blockIdx.x == 0) {
    const int t = threadIdx.x;
    if (t >= 1 && t < GRID) {
      while (__hip_atomic_load(&bar[t * BAR_STRIDE], __ATOMIC_RELAXED,
                               __HIP_MEMORY_SCOPE_AGENT) < n)
        __builtin_amdgcn_s_sleep(2);
      __builtin_amdgcn_fence(__ATOMIC_ACQUIRE, "agent");
    }
    __syncthreads();
    if (t == 0)
      __hip_atomic_store(&bar[BAR_REL_OFF], n, __ATOMIC_RELEASE,
                         __HIP_MEMORY_SCOPE_AGENT);
  } else {
    if (threadIdx.x == 0) {
      __hip_atomic_store(&bar[blockIdx.x * BAR_STRIDE], n, __ATOMIC_RELEASE,
                         __HIP_MEMORY_SCOPE_AGENT);
      while (__hip_atomic_load(&bar[BAR_REL_OFF], __ATOMIC_RELAXED,
                               __HIP_MEMORY_SCOPE_AGENT) < n)
        __builtin_amdgcn_s_sleep(2);
      __builtin_amdgcn_fence(__ATOMIC_ACQUIRE, "agent");
    }
    __syncthreads();
  }
}

// ---------------------------------------------------------------------------
__global__ __launch_bounds__(BLK, 2)
void k_persist(const float* __restrict__ embeds,
               float* __restrict__ cents,      // [K_PAD][64], rows >= 500 zeroed
               float* __restrict__ csq,        // [K_PAD]
               float* __restrict__ esq,        // [N_PTS]
               int* __restrict__ idx,          // [N_PTS] init -1
               int* __restrict__ gcnt,         // [K_C] init 0  (persistent state)
               unsigned long long* __restrict__ acc,  // [K_C][64] int64, init 0 (persistent)
               float* __restrict__ cntf,       // [K_C]
               int* __restrict__ changed,      // [N_ITERS] init 0
               int* __restrict__ bar,          // init 0
               float* __restrict__ out) {
  extern __shared__ __align__(16) char smem[];
  float (*As)[SA] = (float (*)[SA])smem;                       // 64 x 132 f32
  float (*Bs)[SB] = (float (*)[SB])(smem + DIM * SA * 4);      // 64 x 260 f32
  int* bidxs   = (int*)(smem + (DIM * SA + DIM * SB) * 4);     // [128]
  int* chg_pl  = bidxs + 128;                                  // [128]
  int* chg_old = chg_pl + 128;                                 // [128]
  int* chg_cnt = chg_old + 128;                                // [1]
  const int tid = threadIdx.x;
  const int bid = blockIdx.x;
  int bno = 0;

  // ---- pre-phase: esq for all points, csq for initial (padded) centroids ----
  {
    const int w = bid * 8 + (tid >> 6);   // global wave id, 0..2047
    const int d = tid & 63;
    for (int p = w; p < N_PTS; p += GRID * 8) {
      float v = embeds[(size_t)p * DIM + d];
      float s = v * v;
      #pragma unroll
      for (int m = 1; m < 64; m <<= 1) s += __shfl_xor(s, m, 64);
      if (d == 0) esq[p] = s;
    }
    if (w < K_PAD) {
      float v = (w < K_C) ? cents[(size_t)w * DIM + d] : 0.f;
      float s = v * v;
      #pragma unroll
      for (int m = 1; m < 64; m <<= 1) s += __shfl_xor(s, m, 64);
      if (d == 0) csq[w] = (w < K_C) ? s : INFINITY;
    }
  }
  gridbar(bar, ++bno);

  // ---- main loop ----
  for (int it = 0; it < N_ITERS; ++it) {
    // ===== phase A: assignment + DELTA accumulation (blocks 0..234) =========
    if (bid < NTM) {
      const int m0 = bid * TM;
      const int tx = tid & 31, ty = tid >> 5;   // 32 x 16 thread grid
      if (tid == 0) chg_cnt[0] = 0;             // ordered before appends by h-loop syncs

      // stage As (transposed); lane->consecutive-column = conflict-free
      #pragma unroll
      for (int l = 0; l < 4; ++l) {
        int e = tid + l * BLK;          // 0..2047
        int pl = e & 127, d4 = e >> 7;
        int p = m0 + pl;
        float4 v = make_float4(0.f, 0.f, 0.f, 0.f);
        if (p < N_PTS) v = *reinterpret_cast<const float4*>(embeds + (size_t)p * DIM + d4 * 4);
        As[d4 * 4 + 0][pl] = v.x; As[d4 * 4 + 1][pl] = v.y;
        As[d4 * 4 + 2][pl] = v.z; As[d4 * 4 + 3][pl] = v.w;
      }
      float esq_r[8];
      #pragma unroll
      for (int i = 0; i < 8; ++i) {
        int p = m0 + ty * 8 + i;
        esq_r[i] = (p < N_PTS) ? esq[p] : 0.f;
      }

      float best[8]; int bidx[8];
      #pragma unroll
      for (int i = 0; i < 8; ++i) { best[i] = INFINITY; bidx[i] = 0; }

      for (int h = 0; h < 2; ++h) {     // two centroid halves, ascending n
        __syncthreads();                // As ready (h=0) / Bs reuse safe (h=1)
        #pragma unroll
        for (int l = 0; l < 8; ++l) {
          int e2 = tid + l * BLK;       // 0..4095
          int kl = e2 & 255, d4 = e2 >> 8;
          float4 v = *reinterpret_cast<const float4*>(
              cents + (size_t)(h * HALF + kl) * DIM + d4 * 4);
          Bs[d4 * 4 + 0][kl] = v.x; Bs[d4 * 4 + 1][kl] = v.y;
          Bs[d4 * 4 + 2][kl] = v.z; Bs[d4 * 4 + 3][kl] = v.w;
        }
        __syncthreads();

        float acc_r[8][8];
        #pragma unroll
        for (int i = 0; i < 8; ++i)
          #pragma unroll
          for (int j = 0; j < 8; ++j) acc_r[i][j] = 0.f;

        #pragma unroll 8
        for (int d = 0; d < DIM; ++d) {
          float4 a0 = *reinterpret_cast<const float4*>(&As[d][ty * 8]);
          float4 a1 = *reinterpret_cast<const float4*>(&As[d][ty * 8 + 4]);
          float4 b0 = *reinterpret_cast<const float4*>(&Bs[d][tx * 4]);
          float4 b1 = *reinterpret_cast<const float4*>(&Bs[d][128 + tx * 4]);
          float av[8] = {a0.x, a0.y, a0.z, a0.w, a1.x, a1.y, a1.z, a1.w};
          float bv[8] = {b0.x, b0.y, b0.z, b0.w, b1.x, b1.y, b1.z, b1.w};
          #pragma unroll
          for (int i = 0; i < 8; ++i)
            #pragma unroll
            for (int j = 0; j < 8; ++j)
              acc_r[i][j] = fmaf(av[i], bv[j], acc_r[i][j]);
        }

        // distances + running argmin (n ascending within thread, strict '<')
        const int nbase = h * HALF;
        float4 c0 = *reinterpret_cast<const float4*>(&csq[nbase + tx * 4]);
        float4 c1 = *reinterpret_cast<const float4*>(&csq[nbase + 128 + tx * 4]);
        float cv[8] = {c0.x, c0.y, c0.z, c0.w, c1.x, c1.y, c1.z, c1.w};
        #pragma unroll
        for (int g = 0; g < 2; ++g) {
          #pragma unroll
          for (int j = 0; j < 4; ++j) {
            int c = g * 4 + j;
            int n = nbase + g * 128 + tx * 4 + j;
            #pragma unroll
            for (int i = 0; i < 8; ++i) {
              float dd = (esq_r[i] - 2.0f * acc_r[i][c]) + cv[c];
              if (dd < best[i]) { best[i] = dd; bidx[i] = n; }
            }
          }
        }
      }

      // cross-lane argmin over 32 tx lanes; publish idx + changed-point list
      #pragma unroll
      for (int i = 0; i < 8; ++i) {
        float v = best[i]; int bi = bidx[i];
        #pragma unroll
        for (int s = 1; s < 32; s <<= 1) {
          float ov = __shfl_xor(v, s, 64);
          int   oi = __shfl_xor(bi, s, 64);
          if (ov < v || (ov == v && oi < bi)) { v = ov; bi = oi; }
        }
        if (tx == 0) {
          int pl = ty * 8 + i, p = m0 + pl;
          bidxs[pl] = bi;
          if (p < N_PTS) {
            int old = idx[p];
            if (old != bi) {
              idx[p] = bi;
              int slot = atomicAdd(chg_cnt, 1);
              chg_pl[slot] = pl;
              chg_old[slot] = old;
              if (slot == 0)
                __hip_atomic_store(&changed[it], 1, __ATOMIC_RELAXED,
                                   __HIP_MEMORY_SCOPE_AGENT);
            }
          }
        }
      }
      __syncthreads();   // bidxs + change list visible

      // DELTA accumulation: exact int64 +/- for moved points only.
      // lane = dim -> coalesced embeds read; 2 atomics/lane/point.
      {
        const int w = tid >> 6, lane = tid & 63;
        const int cnt = chg_cnt[0];
        for (int i = w; i < cnt; i += 8) {
          int pl = chg_pl[i];
          int old = chg_old[i];
          int k = bidxs[pl];
          float v = embeds[(size_t)(m0 + pl) * DIM + lane];
          long long iv = (long long)__float2int_rn(v * FPSCALE);
          atomicAdd(&acc[(size_t)k * DIM + lane], (unsigned long long)iv);
          if (old >= 0)
            atomicAdd(&acc[(size_t)old * DIM + lane], (unsigned long long)(-iv));
          if (lane == 0) {
            atomicAdd(&gcnt[k], 1);
            if (old >= 0) atomicAdd(&gcnt[old], -1);
          }
        }
      }
    }
    gridbar(bar, ++bno);

    // exact fixed point: no assignment changed => acc/gcnt unchanged =>
    // identical centroids; remaining iterations are identity. Uniform exit.
    if (__hip_atomic_load(&changed[it], __ATOMIC_RELAXED,
                          __HIP_MEMORY_SCOPE_AGENT) == 0)
      break;

    // ===== phase B: centroid update (blocks 0..62, 8 centroids each) ========
    // acc/gcnt are persistent running state; no zeroing.
    if (bid < (K_C + 7) / 8) {
      const int k = bid * 8 + (tid >> 6), d = tid & 63;
      if (k < K_C) {
        long long tot = (long long)acc[(size_t)k * DIM + d];
        int c = gcnt[k];
        float sum_f = (float)((double)tot * INV_FPSCALE);
        float nc = sum_f / ((float)c + 1e-6f);   // matches sums / (counts + EPS)
        cents[(size_t)k * DIM + d] = nc;
        float sq = nc * nc;
        #pragma unroll
        for (int m = 1; m < 64; m <<= 1) sq += __shfl_xor(sq, m, 64);
        if (d == 0) { csq[k] = sq; cntf[k] = (float)c; }
      }
    }
    gridbar(bar, ++bno);
  }

  // ---- final output: [cents 32000][idx as f32 30000][counts 500] ----
  const int tot = K_C * DIM + N_PTS + K_C;
  for (int g = bid * BLK + tid; g < tot; g += GRID * BLK) {
    float v;
    if (g < K_C * DIM) v = cents[g];
    else if (g < K_C * DIM + N_PTS) v = (float)idx[g - K_C * DIM];
    else v = cntf[g - K_C * DIM - N_PTS];
    out[g] = v;
  }
}

// ---------------------------------------------------------------------------
extern "C" void kernel_launch(void* const* d_in, const int* in_sizes, int n_in,
                              void* d_out, int out_size, void* d_ws, size_t ws_size,
                              hipStream_t stream) {
  const float* embeds = (const float*)d_in[0];
  const float* init_c = (const float*)d_in[1];
  float* out = (float*)d_out;

  char* w = (char*)d_ws;
  size_t off = 0;
  auto alloc = [&](size_t bytes) -> void* {
    void* p = w + off;
    off += (bytes + 255) & ~(size_t)255;
    return p;
  };
  float* cents = (float*)alloc((size_t)K_PAD * DIM * sizeof(float));
  float* csq   = (float*)alloc((size_t)K_PAD * sizeof(float));
  float* esq   = (float*)alloc((size_t)N_PTS * sizeof(float));
  int*   idx   = (int*)  alloc((size_t)N_PTS * sizeof(int));
  float* cntf  = (float*)alloc((size_t)K_C * sizeof(float));
  int*   gcnt  = (int*)  alloc((size_t)K_C * sizeof(int));
  unsigned long long* acc =
      (unsigned long long*)alloc((size_t)K_C * DIM * sizeof(unsigned long long));
  int*   chg   = (int*)  alloc((size_t)N_ITERS * sizeof(int));
  int*   bar   = (int*)  alloc((size_t)(BAR_REL_OFF + 64) * sizeof(int));

  // allow >64KB dynamic LDS (160 KiB/CU on gfx950)
  (void)hipFuncSetAttribute((const void*)k_persist,
                            hipFuncAttributeMaxDynamicSharedMemorySize, SMEM_BYTES);

  hipMemsetAsync(cents, 0, (size_t)K_PAD * DIM * sizeof(float), stream);
  hipMemcpyAsync(cents, init_c, (size_t)K_C * DIM * sizeof(float),
                 hipMemcpyDeviceToDevice, stream);
  hipMemsetAsync(gcnt, 0, (size_t)K_C * sizeof(int), stream);
  hipMemsetAsync(acc, 0, (size_t)K_C * DIM * sizeof(unsigned long long), stream);
  hipMemsetAsync(idx, 0xFF, (size_t)N_PTS * sizeof(int), stream);  // -1: changed@it0
  hipMemsetAsync(chg, 0, (size_t)N_ITERS * sizeof(int), stream);
  hipMemsetAsync(bar, 0, (size_t)(BAR_REL_OFF + 64) * sizeof(int), stream);

  k_persist<<<dim3(GRID), dim3(BLK), SMEM_BYTES, stream>>>(
      embeds, cents, csq, esq, idx, gcnt, acc, cntf, chg, bar, out);
}